// Round 13
// baseline (376.342 us; speedup 1.0000x reference)
//
#include <hip/hip_runtime.h>
#include <math.h>

// Problem constants
#define B_    8
#define L_    512
#define K_    16
#define E_    32
#define NH_   64
#define WOFF_ 1

// Workspace layout (floats):
//   qmat  [B][L][32]   @ 0        (131072)
//   kmatT [B][32][L]   @ 131072   (131072)
//   gi    [B][L][192]  @ 524288   (786432)

typedef float v2f __attribute__((ext_vector_type(2)));
typedef float v4f __attribute__((ext_vector_type(4)));

// ---------------------------------------------------------------------------
// Kernel 1: key_emb -> q, k projections. One thread per (b,l). (r8 form)
// ---------------------------------------------------------------------------
__global__ __launch_bounds__(256) void k_embed(
    const float* __restrict__ ts, const float* __restrict__ Wl,
    const float* __restrict__ bl, const float* __restrict__ Wp,
    const float* __restrict__ bp, const float* __restrict__ Wq,
    const float* __restrict__ bq, const float* __restrict__ Wk,
    const float* __restrict__ bk,
    float* __restrict__ qmat, float* __restrict__ kmatT)
{
    __shared__ float WqL[1024], WkL[1024];
    __shared__ float bqL[32], bkL[32], WpL[31], bpL[31];
    __shared__ float wl0, bl0;
    const int tid = threadIdx.x;

    {
        float4 v = ((const float4*)Wq)[tid];
        ((float4*)WqL)[tid] = v;
        float4 u = ((const float4*)Wk)[tid];
        ((float4*)WkL)[tid] = u;
    }
    if (tid < 32) { bqL[tid] = bq[tid]; bkL[tid] = bk[tid]; }
    if (tid < 31) { WpL[tid] = Wp[tid]; bpL[tid] = bp[tid]; }
    if (tid == 0) { wl0 = Wl[0]; bl0 = bl[0]; }
    __syncthreads();

    const int p = blockIdx.x * 256 + tid;      // 0..4095
    const float t = ts[p];
    float e[32];
    e[0] = t * wl0 + bl0;
    #pragma unroll
    for (int j = 1; j < 32; ++j) e[j] = sinf(t * WpL[j - 1] + bpL[j - 1]);

    const int b = p >> 9, l = p & 511;
    float4* qm4 = (float4*)(qmat + (size_t)p * 32);
    float*  kT  = kmatT + (size_t)b * 32 * 512 + l;

    for (int dq = 0; dq < 8; ++dq) {
        float q0 = bqL[4*dq+0], q1 = bqL[4*dq+1], q2 = bqL[4*dq+2], q3 = bqL[4*dq+3];
        float k0 = bkL[4*dq+0], k1 = bkL[4*dq+1], k2 = bkL[4*dq+2], k3 = bkL[4*dq+3];
        const float* wq = &WqL[(4*dq) * 32];
        const float* wk = &WkL[(4*dq) * 32];
        #pragma unroll
        for (int j = 0; j < 32; ++j) {
            const float ej = e[j];
            q0 = fmaf(wq[j],      ej, q0);
            q1 = fmaf(wq[32 + j], ej, q1);
            q2 = fmaf(wq[64 + j], ej, q2);
            q3 = fmaf(wq[96 + j], ej, q3);
            k0 = fmaf(wk[j],      ej, k0);
            k1 = fmaf(wk[32 + j], ej, k1);
            k2 = fmaf(wk[64 + j], ej, k2);
            k3 = fmaf(wk[96 + j], ej, k3);
        }
        qm4[dq] = make_float4(q0, q1, q2, q3);
        kT[(4*dq + 0) * 512] = k0;
        kT[(4*dq + 1) * 512] = k1;
        kT[(4*dq + 2) * 512] = k2;
        kT[(4*dq + 3) * 512] = k3;
    }
}

// ---------------------------------------------------------------------------
// Kernel 2 (attn + gi, high occupancy): r12-verified form, UNCHANGED.
// grid (128 qb, 8 b), 256 thr, 4 waves/SIMD chip-wide.
// ---------------------------------------------------------------------------
__global__ __launch_bounds__(256) void k_attn_gi(
    const float* __restrict__ qmat, const float* __restrict__ kmatT,
    const float* __restrict__ val,  const int*   __restrict__ mark,
    const float* __restrict__ npm,  const float* __restrict__ Wo,
    const float* __restrict__ bo,   const float* __restrict__ Wih,
    const float* __restrict__ bih,  float* __restrict__ gi)
{
    __shared__ float srow[4 * 512];   // per-wave score row (8 KB)
    __shared__ int   cc[512];         // category (-1 if padded)
    __shared__ float vv[512];         // values
    __shared__ float attL[4 * 64];    // this block's 4 att rows
    const int tid = threadIdx.x;
    const int qb  = blockIdx.x;       // 0..127
    const int b   = blockIdx.y;       // 0..7
    const int qb0 = qb * 4;

    for (int k = tid; k < 512; k += 256) {
        const int   m  = mark[b * 512 + k];
        const float np = npm[b * 512 + k];
        cc[k] = (np > 0.0f) ? (m - 1) : -1;
        vv[k] = val[b * 512 + k];
    }
    __syncthreads();

    const int w = tid >> 6, lane = tid & 63;
    const float* kTb = kmatT + (size_t)b * 32 * 512;
    const int q = qb0 + w;            // this wave's q row

    {
        float qr[32];
        const float4* qm4 = (const float4*)(qmat + (size_t)(b * 512 + q) * 32);
        #pragma unroll
        for (int j4 = 0; j4 < 8; ++j4) {
            float4 v = qm4[j4];
            qr[4*j4+0] = v.x; qr[4*j4+1] = v.y; qr[4*j4+2] = v.z; qr[4*j4+3] = v.w;
        }

        float acc[8];
        #pragma unroll
        for (int m = 0; m < 8; ++m) acc[m] = 0.0f;
        #pragma unroll 4
        for (int j = 0; j < 32; ++j) {
            const float* row = kTb + j * 512 + lane;
            const float  qj  = qr[j];
            #pragma unroll
            for (int m = 0; m < 8; ++m) acc[m] = fmaf(qj, row[m * 64], acc[m]);
        }
        #pragma unroll
        for (int m = 0; m < 8; ++m)
            srow[w * 512 + m * 64 + lane] = acc[m] * 0.17677669529663687f;
        // srow slice is wave-private; ds in-order => no barrier needed

        const int c = lane & 15, s = lane >> 4;
        float mx = -1e30f, Z = 0.0f, X = 0.0f;
        const int base = s * 128;
        for (int t = 0; t < 128; ++t) {
            const int k = base + ((t + s) & 127);
            if (cc[k] == c) {
                const float l  = (k <= q + WOFF_) ? srow[w * 512 + k] : 0.0f;
                const float mn = fmaxf(mx, l);
                const float e1 = __expf(l - mn);
                const float sc = __expf(mx - mn);
                Z = Z * sc + e1;
                X = X * sc + e1 * vv[k];
                mx = mn;
            }
        }
        #pragma unroll
        for (int off = 16; off <= 32; off <<= 1) {
            const float mo = __shfl_xor(mx, off);
            const float Zo = __shfl_xor(Z, off);
            const float Xo = __shfl_xor(X, off);
            const float mn = fmaxf(mx, mo);
            const float a0 = __expf(mx - mn);
            const float a1 = __expf(mo - mn);
            Z = Z * a0 + Zo * a1;
            X = X * a0 + Xo * a1;
            mx = mn;
        }
        const float x = (Z > 0.0f) ? X / Z : 0.0f;

        float xs[16];
        #pragma unroll
        for (int c2 = 0; c2 < 16; ++c2) xs[c2] = __shfl(x, c2);

        const float4* wo4 = (const float4*)(Wo + lane * 16);
        float a = bo[lane];
        #pragma unroll
        for (int c4 = 0; c4 < 4; ++c4) {
            float4 v = wo4[c4];
            a += xs[4*c4+0] * v.x + xs[4*c4+1] * v.y + xs[4*c4+2] * v.z + xs[4*c4+3] * v.w;
        }
        attL[w * 64 + lane] = a;      // row stays in LDS
    }
    __syncthreads();                  // all 4 attL rows visible

    // ---- gi part: 4 rows x 192 = 768 outputs, 3 passes of 256 ----
    const size_t out0 = (size_t)(b * 512 + qb0) * 192;
    for (int pp = 0; pp < 3; ++pp) {
        const int p = tid + 256 * pp;
        const int r = p / 192, g = p - r * 192;
        float a0 = bih[g], a1 = 0.f, a2 = 0.f, a3 = 0.f;
        const float* wrow = Wih + g * 64;
        const float* arow = &attL[r * 64];
        #pragma unroll
        for (int j = 0; j < 64; j += 4) {
            a0 = fmaf(arow[j + 0], wrow[j + 0], a0);
            a1 = fmaf(arow[j + 1], wrow[j + 1], a1);
            a2 = fmaf(arow[j + 2], wrow[j + 2], a2);
            a3 = fmaf(arow[j + 3], wrow[j + 3], a3);
        }
        gi[out0 + p] = (a0 + a1) + (a2 + a3);
    }
}

// ---------------------------------------------------------------------------
// Kernel 3: sequential GRU — GATE-SPLIT across 3 waves (3 SIMDs of one CU).
//
// r12 state: single-wave loop bracketed at ~500 VALU + ~320 stall cy/step.
// The 96-pk_fma matvec (192 cy) is the issue floor of ONE wave. Split it:
// wave g in {0,1,2} computes only gate g's matvec (32 pk_fma, 64 VGPR of
// weights), publishes 64 gate values via LDS (parity-double-buffered gx),
// then ALL waves redundantly run the identical scalar tail -> identical h
// (bit-exact: ar/az/hn arrive as complete sums, op sequence unchanged).
// Sync = raw s_barrier + lgkmcnt(0) ONLY (T3/T4 counted-wait pattern):
// gi global loads stay in flight across the barrier (no vmcnt drain — the
// r3 trap). Each wave keeps a private h-broadcast copy (hsw[g]) so only
// the gate exchange crosses waves. sched_barrier(0) fences the asm waits
// (rule #18); ring/parity indices are compile-time (rule #20).
// Fallback if this regresses: r8 single-wave form (174.8 us).
// ---------------------------------------------------------------------------

#define GRU3_STEP(u, DO_REFILL) {                                          \
    /* read own private broadcast copy of h (wave-local, DS in-order) */   \
    v4f hv[16];                                                            \
    _Pragma("unroll")                                                      \
    for (int k = 0; k < 16; ++k) hv[k] = hs4[k];                           \
    const float gown = pown[u];                                            \
    const float gnv  = pgn[u];                                             \
    if (DO_REFILL) {                                                       \
        pown[u] = pf[ownOff];    /* fire-and-forget; crosses barriers */   \
        pgn[u]  = pf[gnOff];                                               \
        pf += 192;                                                         \
    }                                                                      \
    /* own-gate matvec: 32 pk_fma, same j-sequential pair order as r8 */   \
    v2f a2 = {(g == 2) ? bown : (gown + bown), 0.0f};                      \
    _Pragma("unroll")                                                      \
    for (int k = 0; k < 16; ++k) {                                         \
        v2f p0 = __builtin_shufflevector(hv[k], hv[k], 0, 1);              \
        v2f p1 = __builtin_shufflevector(hv[k], hv[k], 2, 3);              \
        a2 = wg[2*k]     * p0 + a2;                                        \
        a2 = wg[2*k + 1] * p1 + a2;                                        \
    }                                                                      \
    gx[u][g][lane] = a2.x + a2.y;                                          \
    /* publish barrier: LDS-only wait — vmcnt loads stay in flight */      \
    asm volatile("s_waitcnt lgkmcnt(0)" ::: "memory");                     \
    __builtin_amdgcn_sched_barrier(0);                                     \
    __builtin_amdgcn_s_barrier();                                          \
    __builtin_amdgcn_sched_barrier(0);                                     \
    const float arS = gx[u][0][lane];                                      \
    const float azS = gx[u][1][lane];                                      \
    const float hnS = gx[u][2][lane];                                      \
    /* tail: identical FP op sequence to r8 -> identical h on all waves */ \
    const float r = __builtin_amdgcn_rcpf(1.0f + __expf(-arS));            \
    const float z = __builtin_amdgcn_rcpf(1.0f + __expf(-azS));            \
    float npre = gnv + r * hnS;                                            \
    npre = fminf(fmaxf(npre, -15.0f), 15.0f);                              \
    const float e2 = __expf(2.0f * npre);                                  \
    const float n  = (e2 - 1.0f) * __builtin_amdgcn_rcpf(e2 + 1.0f);       \
    h = fmaf(z, h - n, n);                                                 \
    hsw_g[lane] = h;                  /* own broadcast copy for t+1 */     \
    if (g == 2) *outp = h;            /* one wave stores output */         \
    outp += 64;                                                            \
}

__global__ __launch_bounds__(192, 1) void k_gru(
    const float* __restrict__ gi, const float* __restrict__ Whh,
    const float* __restrict__ bhh, float* __restrict__ out)
{
    __shared__ float hsw[3][64];      // per-wave private h-broadcast copies
    __shared__ float gx[2][3][64];    // gate exchange, parity double-buffer
    const int tid  = threadIdx.x;
    const int lane = tid & 63;        // 0..63 == h-dim
    const int g    = tid >> 6;        // wave id == gate 0=r,1=z,2=n
    const int b    = blockIdx.x;      // 0..7

    // own gate's weight row (g*64+lane) as 32 x v2f  (64 VGPRs)
    v2f wg[32];
    {
        const v2f* w2 = (const v2f*)(Whh + (size_t)(g * 64 + lane) * 64);
        #pragma unroll
        for (int j = 0; j < 32; ++j) wg[j] = w2[j];
    }
    const float bown = bhh[g * 64 + lane];   // own gate's bias

    const float* gib  = gi  + (size_t)b * 512 * 192;
    float*       outp = out + (size_t)b * 512 * 64 + lane;

    float* hsw_g = hsw[g];
    float h = 0.0f;
    hsw_g[lane] = 0.0f;               // h_{-1}=0 (own copy; DS in-order)

    // gi ring, 2-deep: own-gate value + gn (tail). For g==2 own==gn (dup ok).
    const int ownOff = g * 64 + lane;
    const int gnOff  = 128 + lane;
    float pown[2], pgn[2];
    #pragma unroll
    for (int i = 0; i < 2; ++i) {
        pown[i] = gib[i * 192 + ownOff];
        pgn[i]  = gib[i * 192 + gnOff];
    }
    const float* pf = gib + 2 * 192;

    const v4f* hs4 = (const v4f*)hsw_g;

    // main loop: 255 pairs, steps 0..509 (parity == u since tt is even)
    for (int tt = 0; tt < 510; tt += 2) {
        GRU3_STEP(0, 1)
        GRU3_STEP(1, 1)
    }
    // epilogue: steps 510..511, no refill
    GRU3_STEP(0, 0)
    GRU3_STEP(1, 0)
}

// ---------------------------------------------------------------------------
extern "C" void kernel_launch(void* const* d_in, const int* in_sizes, int n_in,
                              void* d_out, int out_size, void* d_ws, size_t ws_size,
                              hipStream_t stream)
{
    const float* ts   = (const float*)d_in[0];
    const float* val  = (const float*)d_in[1];
    const int*   mark = (const int*)  d_in[2];
    const float* npm  = (const float*)d_in[3];
    const float* Wl   = (const float*)d_in[4];
    const float* bl   = (const float*)d_in[5];
    const float* Wp   = (const float*)d_in[6];
    const float* bp   = (const float*)d_in[7];
    const float* Wq   = (const float*)d_in[8];
    const float* bq   = (const float*)d_in[9];
    const float* Wk   = (const float*)d_in[10];
    const float* bk   = (const float*)d_in[11];
    const float* Wo   = (const float*)d_in[12];
    const float* bo   = (const float*)d_in[13];
    const float* Wih  = (const float*)d_in[14];
    const float* Whh  = (const float*)d_in[15];
    const float* bih  = (const float*)d_in[16];
    const float* bhh  = (const float*)d_in[17];

    float* ws    = (float*)d_ws;
    float* qmat  = ws;                 // 131072
    float* kmatT = ws + 131072;        // 131072
    float* gi    = ws + 524288;        // 786432
    float* out   = (float*)d_out;

    k_embed<<<16, 256, 0, stream>>>(ts, Wl, bl, Wp, bp, Wq, bq, Wk, bk, qmat, kmatT);
    k_attn_gi<<<dim3(128, 8), 256, 0, stream>>>(qmat, kmatT, val, mark, npm,
                                                Wo, bo, Wih, bih, gi);
    k_gru<<<8, 192, 0, stream>>>(gi, Whh, bhh, out);
}

// Round 15
// 338.203 us; speedup vs baseline: 1.1128x; 1.1128x over previous
//
#include <hip/hip_runtime.h>
#include <math.h>

// Problem constants
#define B_    8
#define L_    512
#define K_    16
#define E_    32
#define NH_   64
#define WOFF_ 1

// Workspace layout (floats):
//   qmat  [B][L][32]   @ 0        (131072)
//   kmatT [B][32][L]   @ 131072   (131072)
//   lists [8][64][128] uchar @ float-offset 262144  (65536 B)  row = c*4+s
//   counts[8][64] int        @ float-offset 393216  (2048 B)   idx = c*4+s
//   gi    [B][L][192]  @ 524288   (786432)

typedef float v2f __attribute__((ext_vector_type(2)));
typedef float v4f __attribute__((ext_vector_type(4)));

// ---------------------------------------------------------------------------
// Kernel 1: key_emb -> q, k projections (r8 form) + per-(b,c,s) match-list
// build. Lists record, IN THE EXACT ROTATED SCAN ORDER j=(t+s)&127, which
// k's have category c — the attn softmax then iterates matches only while
// preserving the bit-exact online-softmax accumulation order.
//
// r14 BUG FIX: counts were written at index tid = s*16+c but read at
// c*4+s — every lane got another pair's count (absmax 0.609). Both lists
// and counts now use row index c*4+s consistently.
// ---------------------------------------------------------------------------
__global__ __launch_bounds__(256) void k_embed(
    const float* __restrict__ ts, const float* __restrict__ Wl,
    const float* __restrict__ bl, const float* __restrict__ Wp,
    const float* __restrict__ bp, const float* __restrict__ Wq,
    const float* __restrict__ bq, const float* __restrict__ Wk,
    const float* __restrict__ bk, const int* __restrict__ mark,
    const float* __restrict__ npm,
    float* __restrict__ qmat, float* __restrict__ kmatT,
    unsigned char* __restrict__ lists, int* __restrict__ counts)
{
    __shared__ float WqL[1024], WkL[1024];
    __shared__ float bqL[32], bkL[32], WpL[31], bpL[31];
    __shared__ float wl0, bl0;
    const int tid = threadIdx.x;

    {
        float4 v = ((const float4*)Wq)[tid];
        ((float4*)WqL)[tid] = v;
        float4 u = ((const float4*)Wk)[tid];
        ((float4*)WkL)[tid] = u;
    }
    if (tid < 32) { bqL[tid] = bq[tid]; bkL[tid] = bk[tid]; }
    if (tid < 31) { WpL[tid] = Wp[tid]; bpL[tid] = bp[tid]; }
    if (tid == 0) { wl0 = Wl[0]; bl0 = bl[0]; }
    __syncthreads();

    const int p = blockIdx.x * 256 + tid;      // 0..4095
    const float t = ts[p];
    float e[32];
    e[0] = t * wl0 + bl0;
    #pragma unroll
    for (int j = 1; j < 32; ++j) e[j] = sinf(t * WpL[j - 1] + bpL[j - 1]);

    const int b = p >> 9, l = p & 511;
    float4* qm4 = (float4*)(qmat + (size_t)p * 32);
    float*  kT  = kmatT + (size_t)b * 32 * 512 + l;

    for (int dq = 0; dq < 8; ++dq) {
        float q0 = bqL[4*dq+0], q1 = bqL[4*dq+1], q2 = bqL[4*dq+2], q3 = bqL[4*dq+3];
        float k0 = bkL[4*dq+0], k1 = bkL[4*dq+1], k2 = bkL[4*dq+2], k3 = bkL[4*dq+3];
        const float* wq = &WqL[(4*dq) * 32];
        const float* wk = &WkL[(4*dq) * 32];
        #pragma unroll
        for (int j = 0; j < 32; ++j) {
            const float ej = e[j];
            q0 = fmaf(wq[j],      ej, q0);
            q1 = fmaf(wq[32 + j], ej, q1);
            q2 = fmaf(wq[64 + j], ej, q2);
            q3 = fmaf(wq[96 + j], ej, q3);
            k0 = fmaf(wk[j],      ej, k0);
            k1 = fmaf(wk[32 + j], ej, k1);
            k2 = fmaf(wk[64 + j], ej, k2);
            k3 = fmaf(wk[96 + j], ej, k3);
        }
        qm4[dq] = make_float4(q0, q1, q2, q3);
        kT[(4*dq + 0) * 512] = k0;
        kT[(4*dq + 1) * 512] = k1;
        kT[(4*dq + 2) * 512] = k2;
        kT[(4*dq + 3) * 512] = k3;
    }

    // ---- match-list build: even blocks, threads 0..63, batch = blockIdx/2.
    // Thread (c,s) scans its 128 k's in the rotated order and appends j's.
    if ((blockIdx.x & 1) == 0 && tid < 64) {
        const int bb = blockIdx.x >> 1;       // 0..7
        const int c  = tid & 15, s = tid >> 4;
        const int row = c * 4 + s;            // SAME index for lists & counts
        unsigned char* myl = lists + (size_t)((bb * 64 + row) << 7);
        int cnt = 0;
        for (int tt2 = 0; tt2 < 128; ++tt2) {
            const int j = (tt2 + s) & 127;
            const int k = s * 128 + j;
            const int   m  = mark[bb * 512 + k];
            const float np = npm[bb * 512 + k];
            const int cck = (np > 0.0f) ? (m - 1) : -1;
            if (cck == c) { myl[cnt] = (unsigned char)j; ++cnt; }
        }
        counts[bb * 64 + row] = cnt;          // r14 fix: was [bb*64 + tid]
    }
}

// ---------------------------------------------------------------------------
// Kernel 2 (attn + gi, high occupancy + LIST-DRIVEN softmax):
// grid (128 qb, 8 b), 256 thr, 4 waves/SIMD chip-wide (r12-verified).
// The 128-iteration masked scan (~87% wasted: only ~8/128 k's match a
// lane's category) is replaced by iterating the precomputed match list —
// identical k-visit order => bit-identical mx/Z/X accumulation.
// ---------------------------------------------------------------------------
__global__ __launch_bounds__(256) void k_attn_gi(
    const float* __restrict__ qmat, const float* __restrict__ kmatT,
    const float* __restrict__ val,  const unsigned char* __restrict__ lists,
    const int* __restrict__ counts, const float* __restrict__ Wo,
    const float* __restrict__ bo,   const float* __restrict__ Wih,
    const float* __restrict__ bih,  float* __restrict__ gi)
{
    __shared__ float srow[4 * 512];            // per-wave score row (8 KB)
    __shared__ float vv[512];                  // values
    __shared__ float attL[4 * 64];             // this block's 4 att rows
    __shared__ unsigned char listsL[64 * 132]; // padded rows (33 words each)
    __shared__ int countsL[64];
    const int tid = threadIdx.x;
    const int qb  = blockIdx.x;       // 0..127
    const int b   = blockIdx.y;       // 0..7
    const int qb0 = qb * 4;

    for (int k = tid; k < 512; k += 256)
        vv[k] = val[b * 512 + k];
    // stage this batch's lists: 2048 words, row c4s -> padded row of 33 words
    {
        const unsigned int* gsrc = (const unsigned int*)(lists + ((size_t)b << 13));
        unsigned int* ldst = (unsigned int*)listsL;
        for (int idx = tid; idx < 2048; idx += 256) {
            const int c4s = idx >> 5, wrd = idx & 31;
            ldst[c4s * 33 + wrd] = gsrc[idx];
        }
    }
    if (tid < 64) countsL[tid] = counts[b * 64 + tid];
    __syncthreads();

    const int w = tid >> 6, lane = tid & 63;
    const float* kTb = kmatT + (size_t)b * 32 * 512;
    const int q = qb0 + w;            // this wave's q row

    {
        float qr[32];
        const float4* qm4 = (const float4*)(qmat + (size_t)(b * 512 + q) * 32);
        #pragma unroll
        for (int j4 = 0; j4 < 8; ++j4) {
            float4 v = qm4[j4];
            qr[4*j4+0] = v.x; qr[4*j4+1] = v.y; qr[4*j4+2] = v.z; qr[4*j4+3] = v.w;
        }

        float acc[8];
        #pragma unroll
        for (int m = 0; m < 8; ++m) acc[m] = 0.0f;
        #pragma unroll 4
        for (int j = 0; j < 32; ++j) {
            const float* row = kTb + j * 512 + lane;
            const float  qj  = qr[j];
            #pragma unroll
            for (int m = 0; m < 8; ++m) acc[m] = fmaf(qj, row[m * 64], acc[m]);
        }
        #pragma unroll
        for (int m = 0; m < 8; ++m)
            srow[w * 512 + m * 64 + lane] = acc[m] * 0.17677669529663687f;
        // srow slice is wave-private; ds in-order => no barrier needed

        const int c = lane & 15, s = lane >> 4;
        const int base = s * 128;
        const int nc = countsL[c * 4 + s];
        const unsigned char* myl = &listsL[(c * 4 + s) * 132];
        float mx = -1e30f, Z = 0.0f, X = 0.0f;
        for (int i = 0; i < nc; ++i) {
            const int j = myl[i];
            const int k = base + j;
            const float l  = (k <= q + WOFF_) ? srow[w * 512 + k] : 0.0f;
            const float mn = fmaxf(mx, l);
            const float e1 = __expf(l - mn);
            const float sc = __expf(mx - mn);
            Z = Z * sc + e1;
            X = X * sc + e1 * vv[k];
            mx = mn;
        }
        #pragma unroll
        for (int off = 16; off <= 32; off <<= 1) {
            const float mo = __shfl_xor(mx, off);
            const float Zo = __shfl_xor(Z, off);
            const float Xo = __shfl_xor(X, off);
            const float mn = fmaxf(mx, mo);
            const float a0 = __expf(mx - mn);
            const float a1 = __expf(mo - mn);
            Z = Z * a0 + Zo * a1;
            X = X * a0 + Xo * a1;
            mx = mn;
        }
        const float x = (Z > 0.0f) ? X / Z : 0.0f;

        float xs[16];
        #pragma unroll
        for (int c2 = 0; c2 < 16; ++c2) xs[c2] = __shfl(x, c2);

        const float4* wo4 = (const float4*)(Wo + lane * 16);
        float a = bo[lane];
        #pragma unroll
        for (int c4 = 0; c4 < 4; ++c4) {
            float4 v = wo4[c4];
            a += xs[4*c4+0] * v.x + xs[4*c4+1] * v.y + xs[4*c4+2] * v.z + xs[4*c4+3] * v.w;
        }
        attL[w * 64 + lane] = a;      // row stays in LDS
    }
    __syncthreads();                  // all 4 attL rows visible

    // ---- gi part: 4 rows x 192 = 768 outputs, 3 passes of 256 ----
    const size_t out0 = (size_t)(b * 512 + qb0) * 192;
    for (int pp = 0; pp < 3; ++pp) {
        const int p = tid + 256 * pp;
        const int r = p / 192, g = p - r * 192;
        float a0 = bih[g], a1 = 0.f, a2 = 0.f, a3 = 0.f;
        const float* wrow = Wih + g * 64;
        const float* arow = &attL[r * 64];
        #pragma unroll
        for (int j = 0; j < 64; j += 4) {
            a0 = fmaf(arow[j + 0], wrow[j + 0], a0);
            a1 = fmaf(arow[j + 1], wrow[j + 1], a1);
            a2 = fmaf(arow[j + 2], wrow[j + 2], a2);
            a3 = fmaf(arow[j + 3], wrow[j + 3], a3);
        }
        gi[out0 + p] = (a0 + a1) + (a2 + a3);
    }
}

// ---------------------------------------------------------------------------
// Kernel 3: sequential GRU — r8-verified single-wave form (174.8 us).
// Empirical floor across 8 structural variants (r13 gate-split regressed:
// per-step cross-wave sync costs ~350-400 cy > the 130 cy issue saved).
// ---------------------------------------------------------------------------

#define GRU_STEP(u, DO_REFILL) {                                           \
    v4f hv[16];                                                            \
    _Pragma("unroll")                                                      \
    for (int k = 0; k < 6; ++k) hv[k] = hs4[k];                            \
    const float gr = pr[u], gz = pz[u], gn = pn[u];                        \
    if (DO_REFILL) {                                                       \
        pr[u] = pf[0];                                                     \
        pz[u] = pf[64];                                                    \
        pn[u] = pf[128];                                                   \
        pf += 192;                                                         \
    }                                                                      \
    v2f ar2 = {gr + br, 0.0f};                                             \
    v2f az2 = {gz + bz, 0.0f};                                             \
    v2f an2 = {bn, 0.0f};                                                  \
    _Pragma("unroll")                                                      \
    for (int k = 0; k < 16; ++k) {                                         \
        if (k < 10) hv[k + 6] = hs4[k + 6];                                \
        v2f p0 = __builtin_shufflevector(hv[k], hv[k], 0, 1);              \
        v2f p1 = __builtin_shufflevector(hv[k], hv[k], 2, 3);              \
        ar2 = wr[2*k]     * p0 + ar2;                                      \
        az2 = wz[2*k]     * p0 + az2;                                      \
        an2 = wn[2*k]     * p0 + an2;                                      \
        ar2 = wr[2*k + 1] * p1 + ar2;                                      \
        az2 = wz[2*k + 1] * p1 + az2;                                      \
        an2 = wn[2*k + 1] * p1 + an2;                                      \
    }                                                                      \
    const float ar = ar2.x + ar2.y;                                        \
    const float az = az2.x + az2.y;                                        \
    const float hn = an2.x + an2.y;                                        \
    const float r = __builtin_amdgcn_rcpf(1.0f + __expf(-ar));             \
    const float z = __builtin_amdgcn_rcpf(1.0f + __expf(-az));             \
    float npre = gn + r * hn;                                              \
    npre = fminf(fmaxf(npre, -15.0f), 15.0f);                              \
    const float e2 = __expf(2.0f * npre);                                  \
    const float n  = (e2 - 1.0f) * __builtin_amdgcn_rcpf(e2 + 1.0f);       \
    h = fmaf(z, h - n, n);                                                 \
    hs[lane] = h;                                                          \
    *outp = h;                                                             \
    outp += 64;                                                            \
}

__global__ __launch_bounds__(64, 1) void k_gru(
    const float* __restrict__ gi, const float* __restrict__ Whh,
    const float* __restrict__ bhh, float* __restrict__ out)
{
    __shared__ float hs[64];
    const int lane = threadIdx.x;     // 0..63
    const int b    = blockIdx.x;      // 0..7

    v2f wr[32], wz[32], wn[32];
    {
        const v2f* r2 = (const v2f*)(Whh + (size_t)lane * 64);
        const v2f* z2 = (const v2f*)(Whh + (size_t)(lane + 64) * 64);
        const v2f* n2 = (const v2f*)(Whh + (size_t)(lane + 128) * 64);
        #pragma unroll
        for (int j = 0; j < 32; ++j) {
            wr[j] = r2[j];
            wz[j] = z2[j];
            wn[j] = n2[j];
        }
    }
    const float br = bhh[lane];
    const float bz = bhh[lane + 64];
    const float bn = bhh[lane + 128];

    const float* gib  = gi  + (size_t)b * 512 * 192;
    float*       outp = out + (size_t)b * 512 * 64 + lane;

    float h = 0.0f;
    hs[lane] = 0.0f;                  // h_{-1} = 0 (same wave; DS in-order)

    float pr[2], pz[2], pn[2];
    #pragma unroll
    for (int i = 0; i < 2; ++i) {
        const float* gp = gib + (size_t)i * 192;
        pr[i] = gp[lane];
        pz[i] = gp[lane + 64];
        pn[i] = gp[lane + 128];
    }
    const float* pf = gib + (size_t)2 * 192 + lane;

    const v4f* hs4 = (const v4f*)hs;

    for (int tt = 0; tt < 510; tt += 2) {
        GRU_STEP(0, 1)
        GRU_STEP(1, 1)
    }
    GRU_STEP(0, 0)
    GRU_STEP(1, 0)
}

// ---------------------------------------------------------------------------
extern "C" void kernel_launch(void* const* d_in, const int* in_sizes, int n_in,
                              void* d_out, int out_size, void* d_ws, size_t ws_size,
                              hipStream_t stream)
{
    const float* ts   = (const float*)d_in[0];
    const float* val  = (const float*)d_in[1];
    const int*   mark = (const int*)  d_in[2];
    const float* npm  = (const float*)d_in[3];
    const float* Wl   = (const float*)d_in[4];
    const float* bl   = (const float*)d_in[5];
    const float* Wp   = (const float*)d_in[6];
    const float* bp   = (const float*)d_in[7];
    const float* Wq   = (const float*)d_in[8];
    const float* bq   = (const float*)d_in[9];
    const float* Wk   = (const float*)d_in[10];
    const float* bk   = (const float*)d_in[11];
    const float* Wo   = (const float*)d_in[12];
    const float* bo   = (const float*)d_in[13];
    const float* Wih  = (const float*)d_in[14];
    const float* Whh  = (const float*)d_in[15];
    const float* bih  = (const float*)d_in[16];
    const float* bhh  = (const float*)d_in[17];

    float* ws    = (float*)d_ws;
    float* qmat  = ws;                           // 131072 floats
    float* kmatT = ws + 131072;                  // 131072 floats
    unsigned char* lists = (unsigned char*)(ws + 262144);  // 65536 B
    int*   counts = (int*)(ws + 393216);         // 512 ints
    float* gi    = ws + 524288;                  // 786432 floats
    float* out   = (float*)d_out;

    k_embed<<<16, 256, 0, stream>>>(ts, Wl, bl, Wp, bp, Wq, bq, Wk, bk,
                                    mark, npm, qmat, kmatT, lists, counts);
    k_attn_gi<<<dim3(128, 8), 256, 0, stream>>>(qmat, kmatT, val, lists, counts,
                                                Wo, bo, Wih, bih, gi);
    k_gru<<<8, 64, 0, stream>>>(gi, Whh, bhh, out);
}

// Round 16
// 328.443 us; speedup vs baseline: 1.1458x; 1.0297x over previous
//
#include <hip/hip_runtime.h>
#include <math.h>

// Problem constants
#define B_    8
#define L_    512
#define K_    16
#define E_    32
#define NH_   64
#define WOFF_ 1

// Workspace layout (floats):
//   qmat  [B][L][32]   @ 0        (131072)
//   kmatT [B][32][L]   @ 131072   (131072)
//   gi    [B][L][192]  @ 524288   (786432)

typedef float v2f __attribute__((ext_vector_type(2)));
typedef float v4f __attribute__((ext_vector_type(4)));

// ---------------------------------------------------------------------------
// Kernel 1: key_emb -> q, k projections. One thread per (b,l). (r8 form)
// ---------------------------------------------------------------------------
__global__ __launch_bounds__(256) void k_embed(
    const float* __restrict__ ts, const float* __restrict__ Wl,
    const float* __restrict__ bl, const float* __restrict__ Wp,
    const float* __restrict__ bp, const float* __restrict__ Wq,
    const float* __restrict__ bq, const float* __restrict__ Wk,
    const float* __restrict__ bk,
    float* __restrict__ qmat, float* __restrict__ kmatT)
{
    __shared__ float WqL[1024], WkL[1024];
    __shared__ float bqL[32], bkL[32], WpL[31], bpL[31];
    __shared__ float wl0, bl0;
    const int tid = threadIdx.x;

    {
        float4 v = ((const float4*)Wq)[tid];
        ((float4*)WqL)[tid] = v;
        float4 u = ((const float4*)Wk)[tid];
        ((float4*)WkL)[tid] = u;
    }
    if (tid < 32) { bqL[tid] = bq[tid]; bkL[tid] = bk[tid]; }
    if (tid < 31) { WpL[tid] = Wp[tid]; bpL[tid] = bp[tid]; }
    if (tid == 0) { wl0 = Wl[0]; bl0 = bl[0]; }
    __syncthreads();

    const int p = blockIdx.x * 256 + tid;      // 0..4095
    const float t = ts[p];
    float e[32];
    e[0] = t * wl0 + bl0;
    #pragma unroll
    for (int j = 1; j < 32; ++j) e[j] = sinf(t * WpL[j - 1] + bpL[j - 1]);

    const int b = p >> 9, l = p & 511;
    float4* qm4 = (float4*)(qmat + (size_t)p * 32);
    float*  kT  = kmatT + (size_t)b * 32 * 512 + l;

    for (int dq = 0; dq < 8; ++dq) {
        float q0 = bqL[4*dq+0], q1 = bqL[4*dq+1], q2 = bqL[4*dq+2], q3 = bqL[4*dq+3];
        float k0 = bkL[4*dq+0], k1 = bkL[4*dq+1], k2 = bkL[4*dq+2], k3 = bkL[4*dq+3];
        const float* wq = &WqL[(4*dq) * 32];
        const float* wk = &WkL[(4*dq) * 32];
        #pragma unroll
        for (int j = 0; j < 32; ++j) {
            const float ej = e[j];
            q0 = fmaf(wq[j],      ej, q0);
            q1 = fmaf(wq[32 + j], ej, q1);
            q2 = fmaf(wq[64 + j], ej, q2);
            q3 = fmaf(wq[96 + j], ej, q3);
            k0 = fmaf(wk[j],      ej, k0);
            k1 = fmaf(wk[32 + j], ej, k1);
            k2 = fmaf(wk[64 + j], ej, k2);
            k3 = fmaf(wk[96 + j], ej, k3);
        }
        qm4[dq] = make_float4(q0, q1, q2, q3);
        kT[(4*dq + 0) * 512] = k0;
        kT[(4*dq + 1) * 512] = k1;
        kT[(4*dq + 2) * 512] = k2;
        kT[(4*dq + 3) * 512] = k3;
    }
}

// ---------------------------------------------------------------------------
// Kernel 2 (attn + gi, high occupancy): r12-verified form.
// grid (128 qb, 8 b), 256 thr, 4 waves/SIMD chip-wide. Each block does 4
// q-rows (one per wave); LDS ~13 KB; kmatT/qmat/Wo/Wih/bih read from
// global (L2-hot). srow slices wave-private -> no per-row barriers.
// (r15 list-driven softmax was neutral-to-negative — masked scan is not
// the dominant cost; this simpler form measured best: 326.9 total.)
// ---------------------------------------------------------------------------
__global__ __launch_bounds__(256) void k_attn_gi(
    const float* __restrict__ qmat, const float* __restrict__ kmatT,
    const float* __restrict__ val,  const int*   __restrict__ mark,
    const float* __restrict__ npm,  const float* __restrict__ Wo,
    const float* __restrict__ bo,   const float* __restrict__ Wih,
    const float* __restrict__ bih,  float* __restrict__ gi)
{
    __shared__ float srow[4 * 512];   // per-wave score row (8 KB)
    __shared__ int   cc[512];         // category (-1 if padded)
    __shared__ float vv[512];         // values
    __shared__ float attL[4 * 64];    // this block's 4 att rows
    const int tid = threadIdx.x;
    const int qb  = blockIdx.x;       // 0..127
    const int b   = blockIdx.y;       // 0..7
    const int qb0 = qb * 4;

    for (int k = tid; k < 512; k += 256) {
        const int   m  = mark[b * 512 + k];
        const float np = npm[b * 512 + k];
        cc[k] = (np > 0.0f) ? (m - 1) : -1;
        vv[k] = val[b * 512 + k];
    }
    __syncthreads();

    const int w = tid >> 6, lane = tid & 63;
    const float* kTb = kmatT + (size_t)b * 32 * 512;
    const int q = qb0 + w;            // this wave's q row

    {
        float qr[32];
        const float4* qm4 = (const float4*)(qmat + (size_t)(b * 512 + q) * 32);
        #pragma unroll
        for (int j4 = 0; j4 < 8; ++j4) {
            float4 v = qm4[j4];
            qr[4*j4+0] = v.x; qr[4*j4+1] = v.y; qr[4*j4+2] = v.z; qr[4*j4+3] = v.w;
        }

        float acc[8];
        #pragma unroll
        for (int m = 0; m < 8; ++m) acc[m] = 0.0f;
        #pragma unroll 4
        for (int j = 0; j < 32; ++j) {
            const float* row = kTb + j * 512 + lane;
            const float  qj  = qr[j];
            #pragma unroll
            for (int m = 0; m < 8; ++m) acc[m] = fmaf(qj, row[m * 64], acc[m]);
        }
        #pragma unroll
        for (int m = 0; m < 8; ++m)
            srow[w * 512 + m * 64 + lane] = acc[m] * 0.17677669529663687f;
        // srow slice is wave-private; ds in-order => no barrier needed

        const int c = lane & 15, s = lane >> 4;
        float mx = -1e30f, Z = 0.0f, X = 0.0f;
        const int base = s * 128;
        for (int t = 0; t < 128; ++t) {
            const int k = base + ((t + s) & 127);
            if (cc[k] == c) {
                const float l  = (k <= q + WOFF_) ? srow[w * 512 + k] : 0.0f;
                const float mn = fmaxf(mx, l);
                const float e1 = __expf(l - mn);
                const float sc = __expf(mx - mn);
                Z = Z * sc + e1;
                X = X * sc + e1 * vv[k];
                mx = mn;
            }
        }
        #pragma unroll
        for (int off = 16; off <= 32; off <<= 1) {
            const float mo = __shfl_xor(mx, off);
            const float Zo = __shfl_xor(Z, off);
            const float Xo = __shfl_xor(X, off);
            const float mn = fmaxf(mx, mo);
            const float a0 = __expf(mx - mn);
            const float a1 = __expf(mo - mn);
            Z = Z * a0 + Zo * a1;
            X = X * a0 + Xo * a1;
            mx = mn;
        }
        const float x = (Z > 0.0f) ? X / Z : 0.0f;

        float xs[16];
        #pragma unroll
        for (int c2 = 0; c2 < 16; ++c2) xs[c2] = __shfl(x, c2);

        const float4* wo4 = (const float4*)(Wo + lane * 16);
        float a = bo[lane];
        #pragma unroll
        for (int c4 = 0; c4 < 4; ++c4) {
            float4 v = wo4[c4];
            a += xs[4*c4+0] * v.x + xs[4*c4+1] * v.y + xs[4*c4+2] * v.z + xs[4*c4+3] * v.w;
        }
        attL[w * 64 + lane] = a;      // row stays in LDS
    }
    __syncthreads();                  // all 4 attL rows visible

    // ---- gi part: 4 rows x 192 = 768 outputs, 3 passes of 256 ----
    const size_t out0 = (size_t)(b * 512 + qb0) * 192;
    for (int pp = 0; pp < 3; ++pp) {
        const int p = tid + 256 * pp;
        const int r = p / 192, g = p - r * 192;
        float a0 = bih[g], a1 = 0.f, a2 = 0.f, a3 = 0.f;
        const float* wrow = Wih + g * 64;
        const float* arow = &attL[r * 64];
        #pragma unroll
        for (int j = 0; j < 64; j += 4) {
            a0 = fmaf(arow[j + 0], wrow[j + 0], a0);
            a1 = fmaf(arow[j + 1], wrow[j + 1], a1);
            a2 = fmaf(arow[j + 2], wrow[j + 2], a2);
            a3 = fmaf(arow[j + 3], wrow[j + 3], a3);
        }
        gi[out0 + p] = (a0 + a1) + (a2 + a3);
    }
}

// ---------------------------------------------------------------------------
// Kernel 3: sequential GRU — r8-verified single-wave form (~175 us).
// Empirical floor across nine structural variants: critical path =
// LDS broadcast roundtrip (~120cy) + 3x32-deep fma chains (~192cy) +
// TRANS tail (~150cy) per step; stall < issue so co-residency loses,
// and per-step cross-wave sync costs more than the issue it saves.
// ---------------------------------------------------------------------------

#define GRU_STEP(u, DO_REFILL) {                                           \
    v4f hv[16];                                                            \
    _Pragma("unroll")                                                      \
    for (int k = 0; k < 6; ++k) hv[k] = hs4[k];                            \
    const float gr = pr[u], gz = pz[u], gn = pn[u];                        \
    if (DO_REFILL) {                                                       \
        pr[u] = pf[0];                                                     \
        pz[u] = pf[64];                                                    \
        pn[u] = pf[128];                                                   \
        pf += 192;                                                         \
    }                                                                      \
    v2f ar2 = {gr + br, 0.0f};                                             \
    v2f az2 = {gz + bz, 0.0f};                                             \
    v2f an2 = {bn, 0.0f};                                                  \
    _Pragma("unroll")                                                      \
    for (int k = 0; k < 16; ++k) {                                         \
        if (k < 10) hv[k + 6] = hs4[k + 6];                                \
        v2f p0 = __builtin_shufflevector(hv[k], hv[k], 0, 1);              \
        v2f p1 = __builtin_shufflevector(hv[k], hv[k], 2, 3);              \
        ar2 = wr[2*k]     * p0 + ar2;                                      \
        az2 = wz[2*k]     * p0 + az2;                                      \
        an2 = wn[2*k]     * p0 + an2;                                      \
        ar2 = wr[2*k + 1] * p1 + ar2;                                      \
        az2 = wz[2*k + 1] * p1 + az2;                                      \
        an2 = wn[2*k + 1] * p1 + an2;                                      \
    }                                                                      \
    const float ar = ar2.x + ar2.y;                                        \
    const float az = az2.x + az2.y;                                        \
    const float hn = an2.x + an2.y;                                        \
    const float r = __builtin_amdgcn_rcpf(1.0f + __expf(-ar));             \
    const float z = __builtin_amdgcn_rcpf(1.0f + __expf(-az));             \
    float npre = gn + r * hn;                                              \
    npre = fminf(fmaxf(npre, -15.0f), 15.0f);                              \
    const float e2 = __expf(2.0f * npre);                                  \
    const float n  = (e2 - 1.0f) * __builtin_amdgcn_rcpf(e2 + 1.0f);       \
    h = fmaf(z, h - n, n);                                                 \
    hs[lane] = h;                                                          \
    *outp = h;                                                             \
    outp += 64;                                                            \
}

__global__ __launch_bounds__(64, 1) void k_gru(
    const float* __restrict__ gi, const float* __restrict__ Whh,
    const float* __restrict__ bhh, float* __restrict__ out)
{
    __shared__ float hs[64];
    const int lane = threadIdx.x;     // 0..63
    const int b    = blockIdx.x;      // 0..7

    v2f wr[32], wz[32], wn[32];
    {
        const v2f* r2 = (const v2f*)(Whh + (size_t)lane * 64);
        const v2f* z2 = (const v2f*)(Whh + (size_t)(lane + 64) * 64);
        const v2f* n2 = (const v2f*)(Whh + (size_t)(lane + 128) * 64);
        #pragma unroll
        for (int j = 0; j < 32; ++j) {
            wr[j] = r2[j];
            wz[j] = z2[j];
            wn[j] = n2[j];
        }
    }
    const float br = bhh[lane];
    const float bz = bhh[lane + 64];
    const float bn = bhh[lane + 128];

    const float* gib  = gi  + (size_t)b * 512 * 192;
    float*       outp = out + (size_t)b * 512 * 64 + lane;

    float h = 0.0f;
    hs[lane] = 0.0f;                  // h_{-1} = 0 (same wave; DS in-order)

    float pr[2], pz[2], pn[2];
    #pragma unroll
    for (int i = 0; i < 2; ++i) {
        const float* gp = gib + (size_t)i * 192;
        pr[i] = gp[lane];
        pz[i] = gp[lane + 64];
        pn[i] = gp[lane + 128];
    }
    const float* pf = gib + (size_t)2 * 192 + lane;

    const v4f* hs4 = (const v4f*)hs;

    for (int tt = 0; tt < 510; tt += 2) {
        GRU_STEP(0, 1)
        GRU_STEP(1, 1)
    }
    GRU_STEP(0, 0)
    GRU_STEP(1, 0)
}

// ---------------------------------------------------------------------------
extern "C" void kernel_launch(void* const* d_in, const int* in_sizes, int n_in,
                              void* d_out, int out_size, void* d_ws, size_t ws_size,
                              hipStream_t stream)
{
    const float* ts   = (const float*)d_in[0];
    const float* val  = (const float*)d_in[1];
    const int*   mark = (const int*)  d_in[2];
    const float* npm  = (const float*)d_in[3];
    const float* Wl   = (const float*)d_in[4];
    const float* bl   = (const float*)d_in[5];
    const float* Wp   = (const float*)d_in[6];
    const float* bp   = (const float*)d_in[7];
    const float* Wq   = (const float*)d_in[8];
    const float* bq   = (const float*)d_in[9];
    const float* Wk   = (const float*)d_in[10];
    const float* bk   = (const float*)d_in[11];
    const float* Wo   = (const float*)d_in[12];
    const float* bo   = (const float*)d_in[13];
    const float* Wih  = (const float*)d_in[14];
    const float* Whh  = (const float*)d_in[15];
    const float* bih  = (const float*)d_in[16];
    const float* bhh  = (const float*)d_in[17];

    float* ws    = (float*)d_ws;
    float* qmat  = ws;                 // 131072
    float* kmatT = ws + 131072;        // 131072
    float* gi    = ws + 524288;        // 786432
    float* out   = (float*)d_out;

    k_embed<<<16, 256, 0, stream>>>(ts, Wl, bl, Wp, bp, Wq, bq, Wk, bk, qmat, kmatT);
    k_attn_gi<<<dim3(128, 8), 256, 0, stream>>>(qmat, kmatT, val, mark, npm,
                                                Wo, bo, Wih, bih, gi);
    k_gru<<<8, 64, 0, stream>>>(gi, Whh, bhh, out);
}